// Round 4
// baseline (264.720 us; speedup 1.0000x reference)
//
#include <hip/hip_runtime.h>

// Problem dims (fixed by setup_inputs)
constexpr int Bc = 4, Cc = 128, Hc = 192, Wc = 192;
constexpr int HI = 96, WI = 96;       // half-res inputs
constexpr int NB = 64;                // n_bins
constexpr int NA = 16;                // n_att
constexpr float SCL = 95.0f / 191.0f; // align_corners scale (96->192)

typedef __attribute__((ext_vector_type(8))) short bf16x8;
typedef __attribute__((ext_vector_type(4))) float f32x4;

__device__ __forceinline__ unsigned short f2bf(float f) {
  unsigned u = __builtin_bit_cast(unsigned, f);
  unsigned r = (u + 0x7FFFu + ((u >> 16) & 1u)) >> 16;   // RNE
  return (unsigned short)r;
}

__device__ __forceinline__ float rcp_fast(float r) {
#if defined(__has_builtin)
#if __has_builtin(__builtin_amdgcn_rcpf)
  return __builtin_amdgcn_rcpf(r);
#else
  return 1.0f / r;
#endif
#else
  return 1.0f / r;
#endif
}

// ---------------------------------------------------------------------------
// Prep: w1 (128x128 f32) -> bf16; even rows of w2 (16x128) -> bf16. Into ws.
// ---------------------------------------------------------------------------
__global__ __launch_bounds__(256) void k_prep(
    const float* __restrict__ w1, const float* __restrict__ w2,
    unsigned short* __restrict__ w1bf, unsigned short* __restrict__ w2bf)
{
  const int t = blockIdx.x * 256 + threadIdx.x;   // 0..18431
  if (t < 16384) {
    w1bf[t] = f2bf(w1[t]);
  } else {
    const int u = t - 16384;                      // 0..2047
    const int j = u >> 7, c = u & 127;
    w2bf[u] = f2bf(w2[(2 * j) * 128 + c]);        // even rows only
  }
}

// ---------------------------------------------------------------------------
// Fully fused: h = x + bilinear(pbe); a1 = relu(h@w1^T+b1);
// att = relu(a1@w2e^T+b2e)+1e-3; bc = bilinear(pb); delta; out0; sort; out1.
// One block per (b, y, 64-px x-tile). 256 threads = 4 waves.
// LDS regions (40000 B total -> 4 blocks/CU):
//   A [0,17408):       h_s[64][136] bf16  ->  pbs[64][68] f32 (after af loads)
//   B [17408,35840):   row_s[128][36] f32 -> a1_s[64][136] bf16 -> srt[64][64]
//   C [35840,40000):   att_s[16][65] f32
// ---------------------------------------------------------------------------
__global__ __launch_bounds__(256) void k_fused(
    const float* __restrict__ x, const float* __restrict__ pbe,
    const float* __restrict__ pb,
    const unsigned short* __restrict__ w1bf, const float* __restrict__ b1,
    const unsigned short* __restrict__ w2bf, const float* __restrict__ b2,
    float* __restrict__ out0, float* __restrict__ out1)
{
  constexpr int PH = 136;
  __shared__ __align__(16) unsigned char smem[40000];
  unsigned short* h_s   = (unsigned short*)smem;             // [64][PH]
  float*          pbs   = (float*)smem;                      // [64][68] (aliases h_s)
  float*          row_s = (float*)(smem + 17408);            // [128][36]
  unsigned short* a1_s  = (unsigned short*)(smem + 17408);   // [64][PH] (aliases row_s)
  float*          srt   = (float*)(smem + 17408);            // [64][64] (aliases a1_s)
  float*          att_s = (float*)(smem + 35840);            // [16][65]

  const int tid = threadIdx.x;
  const int xg0 = blockIdx.x * 64;
  const int y = blockIdx.y;
  const int b = blockIdx.z;

  const float ysf = y * SCL;
  const int y0 = (int)ysf;
  const int y1 = min(y0 + 1, HI - 1);
  const float wy = ysf - (float)y0;
  const int xi0 = (int)(xg0 * SCL);

  // ---- phase 1: row_s[c][xi] = y-interp of pbe (coalesced loads)
  #pragma unroll
  for (int i = 0; i < 18; ++i) {
    const int f = tid + 256 * i;        // 0..4607
    const int c = f / 36;
    const int xi = f - c * 36;
    const int xgl = min(xi0 + xi, WI - 1);
    const float* p = pbe + (size_t)(b * Cc + c) * (HI * WI);
    const float top = p[y0 * WI + xgl];
    const float bot = p[y1 * WI + xgl];
    row_s[c * 36 + xi] = top + wy * (bot - top);
  }
  __syncthreads();

  // ---- phase 2: h_s[px][c] = bf16(x + x-interp(row_s))  (x via float4)
  #pragma unroll
  for (int i = 0; i < 8; ++i) {
    const int f4 = tid + 256 * i;       // 0..2047
    const int c = f4 >> 4;              // 0..127
    const int q = f4 & 15;              // px quad
    const float4 xv = *(const float4*)&x[((size_t)(b * Cc + c) * Hc + y) * Wc + xg0 + 4 * q];
    const float xa[4] = {xv.x, xv.y, xv.z, xv.w};
    #pragma unroll
    for (int r = 0; r < 4; ++r) {
      const int px = 4 * q + r;
      const float xsf = (float)(xg0 + px) * SCL;
      const int x0 = (int)xsf;
      const float wx = xsf - (float)x0;
      const int xl = x0 - xi0;          // 0..32, xl+1 <= 35
      const float v0 = row_s[c * 36 + xl];
      const float v1 = row_s[c * 36 + xl + 1];
      h_s[px * PH + c] = f2bf(xa[r] + v0 + wx * (v1 - v0));
    }
  }
  __syncthreads();   // h_s complete; row_s dead

  const int lane = tid & 63;
  const int wv = tid >> 6;        // wave id 0..3
  const int ln = lane & 15;
  const int qd = lane >> 4;
  const int m0 = wv * 16;

  // ---- A-fragments for GEMM1 from h_s
  bf16x8 af[4];
  #pragma unroll
  for (int kt = 0; kt < 4; ++kt)
    af[kt] = *(const bf16x8*)&h_s[(m0 + ln) * PH + kt * 32 + qd * 8];
  __syncthreads();   // h_s dead -> region A reusable as pbs

  // ---- issue pb loads early (17 per thread; LDS writes deferred past GEMMs)
  float pbv[17];
  #pragma unroll
  for (int i = 0; i < 17; ++i) {
    const int u = tid + 256 * i;        // 0..4351 == k*68 + (r*34 + xi)
    const int k = u / 68;
    const int rem = u - k * 68;
    const int r = (rem >= 34) ? 1 : 0;
    const int xi = rem - 34 * r;
    const int xgl = min(xi0 + xi, WI - 1);
    const int yr = r ? y1 : y0;
    pbv[i] = pb[(size_t)(b * NB + k) * (HI * WI) + yr * WI + xgl];
  }

  // ---- GEMM1: C[64m][128n] = h[64m][128k] * w1[128n][128k]^T
  f32x4 acc[8];
  #pragma unroll
  for (int nt = 0; nt < 8; ++nt) acc[nt] = f32x4{0.f, 0.f, 0.f, 0.f};
  #pragma unroll
  for (int nt = 0; nt < 8; ++nt) {
    #pragma unroll
    for (int kt = 0; kt < 4; ++kt) {
      const bf16x8 bf = *(const bf16x8*)&w1bf[(nt * 16 + ln) * 128 + kt * 32 + qd * 8];
      acc[nt] = __builtin_amdgcn_mfma_f32_16x16x32_bf16(af[kt], bf, acc[nt], 0, 0, 0);
    }
  }

  // epilogue: relu(+bias) -> a1_s (bf16). Wave-private rows, no barrier.
  #pragma unroll
  for (int nt = 0; nt < 8; ++nt) {
    const int n = nt * 16 + ln;
    const float bias = b1[n];
    #pragma unroll
    for (int r = 0; r < 4; ++r) {
      const int m = m0 + qd * 4 + r;
      a1_s[m * PH + n] = f2bf(fmaxf(acc[nt][r] + bias, 0.f));
    }
  }

  // ---- GEMM2: att[64m][16j] = a1[64m][128k] * w2e[16j][128k]^T
  f32x4 acc2 = f32x4{0.f, 0.f, 0.f, 0.f};
  #pragma unroll
  for (int kt = 0; kt < 4; ++kt) {
    const bf16x8 a2 = *(const bf16x8*)&a1_s[(m0 + ln) * PH + kt * 32 + qd * 8];
    const bf16x8 b2f = *(const bf16x8*)&w2bf[ln * 128 + kt * 32 + qd * 8];
    acc2 = __builtin_amdgcn_mfma_f32_16x16x32_bf16(a2, b2f, acc2, 0, 0, 0);
  }
  {
    const float bias2 = b2[2 * ln];
    #pragma unroll
    for (int r = 0; r < 4; ++r) {
      const int px = m0 + qd * 4 + r;
      att_s[ln * 65 + px] = fmaxf(acc2[r] + bias2, 0.f) + 0.001f;   // j-major
    }
  }

  // ---- pbs LDS writes (layout [k][68] contiguous => pbs[u] = pbv[i])
  #pragma unroll
  for (int i = 0; i < 17; ++i)
    pbs[tid + 256 * i] = pbv[i];
  __syncthreads();   // att_s + pbs ready; a1_s dead -> srt may reuse

  // ---- delta phase: thread = (px = tid&63, 16 contiguous bins per wave)
  const int px = tid & 63;
  const int xg = xg0 + px;
  {
    const float xsf = xg * SCL;
    const int x0 = (int)xsf;
    const float wx = xsf - (float)x0;
    const int xl = x0 - xi0;            // 0..32, xl+1 <= 33

    float am[16];
    #pragma unroll
    for (int j = 0; j < NA; ++j) am[j] = att_s[j * 65 + px];

    const size_t obase = (size_t)(b * NB) * (Hc * Wc) + (size_t)y * Wc + xg;
    #pragma unroll
    for (int i = 0; i < 16; ++i) {
      const int k = wv * 16 + i;
      const float v00 = pbs[k * 68 + xl],      v01 = pbs[k * 68 + xl + 1];
      const float v10 = pbs[k * 68 + 34 + xl], v11 = pbs[k * 68 + 34 + xl + 1];
      const float top = v00 + wx * (v01 - v00);
      const float bot = v10 + wx * (v11 - v10);
      const float bc = top + wy * (bot - top);
      float delta = 0.f;
      #pragma unroll
      for (int j = 0; j < NA; ++j) {
        const float d = am[j] - bc;
        const float rq = fmaf(300.f * d, d, 1.f);
        delta = fmaf(d, rcp_fast(rq), delta);
      }
      const float bnc = fmaf(delta, 1.f / 16.f, bc);
      out0[obase + (size_t)k * (Hc * Wc)] = bnc;
      srt[k * 64 + px] = fmaf(9.999f, bnc, 0.001f);
    }
  }
  __syncthreads();

  // ---- sort phase: 128 threads; thread = (px, half of 32 bins)
  float sv[32];
  const int half = tid >> 6;            // 0 or 1 for tid<128
  if (tid < 128) {
    #pragma unroll
    for (int i = 0; i < 32; ++i) sv[i] = srt[(half * 32 + i) * 64 + px];
    const bool desc = (half == 1);
    // in-register bitonic sort of 32 (half0 asc, half1 desc)
    #pragma unroll
    for (int size = 2; size <= 32; size <<= 1) {
      #pragma unroll
      for (int stride = size >> 1; stride >= 1; stride >>= 1) {
        #pragma unroll
        for (int i = 0; i < 32; ++i) {
          if ((i & stride) == 0) {
            const int j = i | stride;
            const bool up = (((i & size) == 0) != desc);
            const float a = sv[i], c = sv[j];
            const float lo = fminf(a, c), hi = fmaxf(a, c);
            sv[i] = up ? lo : hi;
            sv[j] = up ? hi : lo;
          }
        }
      }
    }
    #pragma unroll
    for (int i = 0; i < 32; ++i) srt[(half * 32 + i) * 64 + px] = sv[i];
  }
  __syncthreads();

  if (tid < 128) {
    // stride-32 merge step (cross-thread via LDS), then strides 16..1 in regs
    #pragma unroll
    for (int i = 0; i < 32; ++i) {
      const float partner = srt[((1 - half) * 32 + i) * 64 + px];
      sv[i] = half ? fmaxf(sv[i], partner) : fminf(sv[i], partner);
    }
    #pragma unroll
    for (int stride = 16; stride >= 1; stride >>= 1) {
      #pragma unroll
      for (int i = 0; i < 32; ++i) {
        if ((i & stride) == 0) {
          const int j = i | stride;
          const float a = sv[i], c = sv[j];
          sv[i] = fminf(a, c);
          sv[j] = fmaxf(a, c);
        }
      }
    }
    const size_t obase = (size_t)(b * NB) * (Hc * Wc) + (size_t)y * Wc + xg0 + px;
    #pragma unroll
    for (int i = 0; i < 32; ++i) {
      const int k = half * 32 + i;
      out1[obase + (size_t)k * (Hc * Wc)] = fminf(fmaxf(sv[i], 0.001f), 10.0f);
    }
  }
}

// ---------------------------------------------------------------------------
extern "C" void kernel_launch(void* const* d_in, const int* in_sizes, int n_in,
                              void* d_out, int out_size, void* d_ws, size_t ws_size,
                              hipStream_t stream) {
  const float* x   = (const float*)d_in[0];   // (4,128,192,192)
  const float* pb  = (const float*)d_in[1];   // (4,64,96,96)
  const float* pbe = (const float*)d_in[2];   // (4,128,96,96)
  const float* w1  = (const float*)d_in[3];   // (128,128)
  const float* b1  = (const float*)d_in[4];   // (128,)
  const float* w2  = (const float*)d_in[5];   // (32,128)
  const float* b2  = (const float*)d_in[6];   // (32,)

  float* out0 = (float*)d_out;                       // bin_new_centers
  float* out1 = out0 + (size_t)Bc * NB * Hc * Wc;    // bin_centers

  unsigned short* w1bf = (unsigned short*)d_ws;      // 32 KB
  unsigned short* w2bf = w1bf + 16384;               // 4 KB

  k_prep<<<72, 256, 0, stream>>>(w1, w2, w1bf, w2bf);

  dim3 grid(Wc / 64, Hc, Bc);
  k_fused<<<grid, 256, 0, stream>>>(x, pbe, pb, w1bf, b1, w2bf, b2, out0, out1);
}

// Round 5
// 242.547 us; speedup vs baseline: 1.0914x; 1.0914x over previous
//
#include <hip/hip_runtime.h>

// Problem dims (fixed by setup_inputs)
constexpr int Bc = 4, Cc = 128, Hc = 192, Wc = 192;
constexpr int HI = 96, WI = 96;       // half-res inputs
constexpr int NB = 64;                // n_bins
constexpr int NA = 16;                // n_att
constexpr float SCL = 95.0f / 191.0f; // align_corners scale (96->192)

typedef __attribute__((ext_vector_type(8))) short bf16x8;
typedef __attribute__((ext_vector_type(4))) float f32x4;

__device__ __forceinline__ unsigned short f2bf(float f) {
  unsigned u = __builtin_bit_cast(unsigned, f);
  unsigned r = (u + 0x7FFFu + ((u >> 16) & 1u)) >> 16;   // RNE
  return (unsigned short)r;
}
__device__ __forceinline__ float bf2f(unsigned short h) {
  unsigned u = ((unsigned)h) << 16;
  return __builtin_bit_cast(float, u);
}
__device__ __forceinline__ float rcp_fast(float r) {
#if defined(__has_builtin)
#if __has_builtin(__builtin_amdgcn_rcpf)
  return __builtin_amdgcn_rcpf(r);
#else
  return 1.0f / r;
#endif
#else
  return 1.0f / r;
#endif
}

// ---------------------------------------------------------------------------
// Prep: w1 (128x128 f32) -> bf16; even rows of w2 (16x128) -> bf16. Into ws.
// ---------------------------------------------------------------------------
__global__ __launch_bounds__(256) void k_prep(
    const float* __restrict__ w1, const float* __restrict__ w2,
    unsigned short* __restrict__ w1bf, unsigned short* __restrict__ w2bf)
{
  const int t = blockIdx.x * 256 + threadIdx.x;   // 0..18431
  if (t < 16384) {
    w1bf[t] = f2bf(w1[t]);
  } else {
    const int u = t - 16384;                      // 0..2047
    const int j = u >> 7, c = u & 127;
    w2bf[u] = f2bf(w2[(2 * j) * 128 + c]);        // even rows only
  }
}

// ---------------------------------------------------------------------------
// K1 (MFMA): h = x + bilinear(pbe); a1 = relu(h@w1^T+b1);
//            att = relu(a1@w2e^T+b2e)+1e-3  -> att_ws[b][y][x][j]
// One block per (b, y, 64-px x-tile). 256 threads = 4 waves; wave wv owns
// the 16-px m-tile [wv*16, wv*16+16).
// A-fragments are built DIRECTLY in registers (no h_s tile, no conflicted
// LDS writes): x via per-lane scalar loads (coalesced along px within each
// 16-lane group), pe from a bf16 y-interp row cache in LDS.
// LDS: 17408 B total -> rowb[128][36] bf16 (9216 B), then (post-barrier)
// a1_s[64][136] bf16 aliases the whole region.
// ---------------------------------------------------------------------------
__global__ __launch_bounds__(256, 4) void k_att(
    const float* __restrict__ x, const float* __restrict__ pbe,
    const unsigned short* __restrict__ w1bf, const float* __restrict__ b1,
    const unsigned short* __restrict__ w2bf, const float* __restrict__ b2,
    float* __restrict__ att)
{
  constexpr int PH = 136;
  __shared__ __align__(16) unsigned char smem[64 * PH * 2];     // 17408 B
  unsigned short* rowb = (unsigned short*)smem;                 // [128][36] bf16
  unsigned short* a1_s = (unsigned short*)smem;                 // [64][PH] (after barrier)

  const int tid = threadIdx.x;
  const int xg0 = blockIdx.x * 64;
  const int y = blockIdx.y;
  const int b = blockIdx.z;

  const float ysf = y * SCL;
  const int y0 = (int)ysf;
  const int y1 = min(y0 + 1, HI - 1);
  const float wy = ysf - (float)y0;
  const int xi0 = (int)(xg0 * SCL);

  // ---- phase 1: rowb[c][xi] = bf16(y-interp of pbe)
  #pragma unroll
  for (int i = 0; i < 18; ++i) {
    const int f = tid + 256 * i;        // 0..4607
    const int c = f / 36;
    const int xi = f - c * 36;
    const int xgl = min(xi0 + xi, WI - 1);
    const float* p = pbe + (size_t)(b * Cc + c) * (HI * WI);
    const float top = p[y0 * WI + xgl];
    const float bot = p[y1 * WI + xgl];
    rowb[c * 36 + xi] = f2bf(top + wy * (bot - top));
  }
  __syncthreads();

  const int lane = tid & 63;
  const int wv = tid >> 6;        // wave id 0..3
  const int ln = lane & 15;
  const int qd = lane >> 4;
  const int m0 = wv * 16;

  const int px = m0 + ln;
  const int xg = xg0 + px;
  const float xsf = (float)xg * SCL;
  const int x0i = (int)xsf;
  const float wx = xsf - (float)x0i;
  const int xl = x0i - xi0;             // 0..32, xl+1 <= 33

  // ---- build A-fragments in registers: af[kt][j] = h(px, c=kt*32+qd*8+j)
  bf16x8 af[4];
  #pragma unroll
  for (int kt = 0; kt < 4; ++kt) {
    #pragma unroll
    for (int j = 0; j < 8; ++j) {
      const int c = kt * 32 + qd * 8 + j;
      const float xv = x[((size_t)(b * Cc + c) * Hc + y) * Wc + xg];
      const float v0 = bf2f(rowb[c * 36 + xl]);
      const float v1 = bf2f(rowb[c * 36 + xl + 1]);
      af[kt][j] = (short)f2bf(xv + v0 + wx * (v1 - v0));
    }
  }
  __syncthreads();   // rowb dead -> region reusable as a1_s

  // ---- GEMM1: C[64m][128n] = h[64m][128k] * w1[128n][128k]^T (B from global)
  f32x4 acc[8];
  #pragma unroll
  for (int nt = 0; nt < 8; ++nt) acc[nt] = f32x4{0.f, 0.f, 0.f, 0.f};
  #pragma unroll
  for (int nt = 0; nt < 8; ++nt) {
    #pragma unroll
    for (int kt = 0; kt < 4; ++kt) {
      const bf16x8 bf = *(const bf16x8*)&w1bf[(nt * 16 + ln) * 128 + kt * 32 + qd * 8];
      acc[nt] = __builtin_amdgcn_mfma_f32_16x16x32_bf16(af[kt], bf, acc[nt], 0, 0, 0);
    }
  }

  // epilogue: relu(+bias) -> a1_s (bf16). Wave writes only its own 16 rows.
  #pragma unroll
  for (int nt = 0; nt < 8; ++nt) {
    const int n = nt * 16 + ln;
    const float bias = b1[n];
    #pragma unroll
    for (int r = 0; r < 4; ++r) {
      const int m = m0 + qd * 4 + r;
      a1_s[m * PH + n] = f2bf(fmaxf(acc[nt][r] + bias, 0.f));
    }
  }
  // no __syncthreads: each wave reads back only rows it wrote (DS in-order/wave)

  // ---- GEMM2: att[64m][16j] = a1[64m][128k] * w2e[16j][128k]^T
  f32x4 acc2 = f32x4{0.f, 0.f, 0.f, 0.f};
  #pragma unroll
  for (int kt = 0; kt < 4; ++kt) {
    const bf16x8 a2 = *(const bf16x8*)&a1_s[(m0 + ln) * PH + kt * 32 + qd * 8];
    const bf16x8 b2f = *(const bf16x8*)&w2bf[ln * 128 + kt * 32 + qd * 8];
    acc2 = __builtin_amdgcn_mfma_f32_16x16x32_bf16(a2, b2f, acc2, 0, 0, 0);
  }
  const float bias2 = b2[2 * ln];
  #pragma unroll
  for (int r = 0; r < 4; ++r) {
    const int opx = m0 + qd * 4 + r;
    const float v = fmaxf(acc2[r] + bias2, 0.f) + 0.001f;
    att[((size_t)((b * Hc + y) * Wc) + xg0 + opx) * NA + ln] = v;
  }
}

// ---------------------------------------------------------------------------
// K2: block = one image row (192 threads), thread = pixel.
// pb rows for all 64 bins staged to LDS (coalesced float4), delta with 4
// independent bins in flight (4 parallel rcp chains), register bitonic sort.
// launch_bounds(192,2): VGPR cap 256 -> no spill for v[64].
// ---------------------------------------------------------------------------
__global__ __launch_bounds__(192, 2) void k_bins(
    const float* __restrict__ pb, const float* __restrict__ att,
    float* __restrict__ out0, float* __restrict__ out1)
{
  __shared__ __align__(16) float pbs[NB][2][WI];   // 48 KB

  const int tid = threadIdx.x;      // = xg
  const int y = blockIdx.x;
  const int b = blockIdx.y;

  const float ysf = y * SCL;
  const int y0 = (int)ysf;
  const int y1 = min(y0 + 1, HI - 1);
  const float wy = ysf - (float)y0;

  // ---- stage pb rows y0,y1 for all 64 bins: 3072 float4, 16 per thread
  #pragma unroll
  for (int i = 0; i < 16; ++i) {
    const int u = tid + 192 * i;          // 0..3071
    const int k = u / 48;
    const int rem = u - k * 48;
    const int r = rem / 24;
    const int xi4 = rem - r * 24;
    const int yr = r ? y1 : y0;
    const float4 v = *(const float4*)&pb[(size_t)(b * NB + k) * (HI * WI) + yr * WI + xi4 * 4];
    *(float4*)&pbs[k][r][xi4 * 4] = v;
  }

  // att for this pixel: 16 floats, contiguous (overlap with staging)
  float am[16];
  {
    const float4* ap = (const float4*)(att + ((size_t)((b * Hc + y) * Wc) + tid) * NA);
    const float4 a0 = ap[0], a1 = ap[1], a2 = ap[2], a3 = ap[3];
    am[0] = a0.x;  am[1] = a0.y;  am[2] = a0.z;  am[3] = a0.w;
    am[4] = a1.x;  am[5] = a1.y;  am[6] = a1.z;  am[7] = a1.w;
    am[8] = a2.x;  am[9] = a2.y;  am[10] = a2.z; am[11] = a2.w;
    am[12] = a3.x; am[13] = a3.y; am[14] = a3.z; am[15] = a3.w;
  }
  __syncthreads();

  const float xsf = tid * SCL;
  const int x0 = (int)xsf;          // <= 94
  const float wx = xsf - (float)x0;

  const size_t obase = (size_t)(b * NB) * (Hc * Wc) + (size_t)y * Wc + tid;
  float v[NB];

  // ---- delta: 4 bins in flight -> 4 independent rcp chains
  #pragma unroll
  for (int kb = 0; kb < NB; kb += 4) {
    float bc[4], dl[4];
    #pragma unroll
    for (int q = 0; q < 4; ++q) {
      const int k = kb + q;
      const float v00 = pbs[k][0][x0], v01 = pbs[k][0][x0 + 1];
      const float v10 = pbs[k][1][x0], v11 = pbs[k][1][x0 + 1];
      const float top = v00 + wx * (v01 - v00);
      const float bot = v10 + wx * (v11 - v10);
      bc[q] = top + wy * (bot - top);
      dl[q] = 0.f;
    }
    #pragma unroll
    for (int j = 0; j < NA; ++j) {
      const float a = am[j];
      #pragma unroll
      for (int q = 0; q < 4; ++q) {
        const float d = a - bc[q];
        const float rq = fmaf(300.f * d, d, 1.f);
        dl[q] = fmaf(d, rcp_fast(rq), dl[q]);
      }
    }
    #pragma unroll
    for (int q = 0; q < 4; ++q) {
      const float bnc = fmaf(dl[q], 1.f / 16.f, bc[q]);
      out0[obase + (size_t)(kb + q) * (Hc * Wc)] = bnc;
      v[kb + q] = fmaf(9.999f, bnc, 0.001f);
    }
  }

  // ---- fully-unrolled bitonic sort on 64 registers (ascending)
  #pragma unroll
  for (int size = 2; size <= NB; size <<= 1) {
    #pragma unroll
    for (int stride = size >> 1; stride >= 1; stride >>= 1) {
      #pragma unroll
      for (int i = 0; i < NB; ++i) {
        if ((i & stride) == 0) {
          const int j = i | stride;
          const bool asc = ((i & size) == 0);
          const float a = v[i], c = v[j];
          const float lo = fminf(a, c), hi = fmaxf(a, c);
          v[i] = asc ? lo : hi;
          v[j] = asc ? hi : lo;
        }
      }
    }
  }

  #pragma unroll
  for (int k = 0; k < NB; ++k) {
    out1[obase + (size_t)k * (Hc * Wc)] = fminf(fmaxf(v[k], 0.001f), 10.0f);
  }
}

// ---------------------------------------------------------------------------
extern "C" void kernel_launch(void* const* d_in, const int* in_sizes, int n_in,
                              void* d_out, int out_size, void* d_ws, size_t ws_size,
                              hipStream_t stream) {
  const float* x   = (const float*)d_in[0];   // (4,128,192,192)
  const float* pb  = (const float*)d_in[1];   // (4,64,96,96)
  const float* pbe = (const float*)d_in[2];   // (4,128,96,96)
  const float* w1  = (const float*)d_in[3];   // (128,128)
  const float* b1  = (const float*)d_in[4];   // (128,)
  const float* w2  = (const float*)d_in[5];   // (32,128)
  const float* b2  = (const float*)d_in[6];   // (32,)

  float* out0 = (float*)d_out;                       // bin_new_centers
  float* out1 = out0 + (size_t)Bc * NB * Hc * Wc;    // bin_centers

  // ws layout: [w1bf 32KB][w2bf 4KB][pad to 64KB][att f32 9.4MB]
  unsigned short* w1bf = (unsigned short*)d_ws;
  unsigned short* w2bf = w1bf + 16384;
  float* att = (float*)((char*)d_ws + 65536);        // [b][y][x][j]

  k_prep<<<72, 256, 0, stream>>>(w1, w2, w1bf, w2bf);

  dim3 g1(Wc / 64, Hc, Bc);
  k_att<<<g1, 256, 0, stream>>>(x, pbe, w1bf, b1, w2bf, b2, att);

  dim3 g2(Hc, Bc);
  k_bins<<<g2, 192, 0, stream>>>(pb, att, out0, out1);
}

// Round 6
// 237.992 us; speedup vs baseline: 1.1123x; 1.0191x over previous
//
#include <hip/hip_runtime.h>

// Problem dims (fixed by setup_inputs)
constexpr int Bc = 4, Cc = 128, Hc = 192, Wc = 192;
constexpr int HI = 96, WI = 96;       // half-res inputs
constexpr int NB = 64;                // n_bins
constexpr int NA = 16;                // n_att
constexpr float SCL = 95.0f / 191.0f; // align_corners scale (96->192)

typedef __attribute__((ext_vector_type(8))) short bf16x8;
typedef __attribute__((ext_vector_type(4))) float f32x4;

__device__ __forceinline__ unsigned short f2bf(float f) {
  unsigned u = __builtin_bit_cast(unsigned, f);
  unsigned r = (u + 0x7FFFu + ((u >> 16) & 1u)) >> 16;   // RNE
  return (unsigned short)r;
}
__device__ __forceinline__ float rcp_fast(float r) {
#if defined(__has_builtin)
#if __has_builtin(__builtin_amdgcn_rcpf)
  return __builtin_amdgcn_rcpf(r);
#else
  return 1.0f / r;
#endif
#else
  return 1.0f / r;
#endif
}

// ---------------------------------------------------------------------------
// Prep: w1 (128x128 f32) -> bf16; even rows of w2 (16x128) -> bf16. Into ws.
// ---------------------------------------------------------------------------
__global__ __launch_bounds__(256) void k_prep(
    const float* __restrict__ w1, const float* __restrict__ w2,
    unsigned short* __restrict__ w1bf, unsigned short* __restrict__ w2bf)
{
  const int t = blockIdx.x * 256 + threadIdx.x;   // 0..18431
  if (t < 16384) {
    w1bf[t] = f2bf(w1[t]);
  } else {
    const int u = t - 16384;                      // 0..2047
    const int j = u >> 7, c = u & 127;
    w2bf[u] = f2bf(w2[(2 * j) * 128 + c]);        // even rows only
  }
}

// ---------------------------------------------------------------------------
// K1 (MFMA): h = x + bilinear(pbe); a1 = relu(h@w1^T+b1);
//            att = relu(a1@w2e^T+b2e)+1e-3  -> att_ws[b][y][x][j]
// One block per (b, y, 64-px x-tile). 256 threads = 4 waves.
// x loads hoisted ABOVE phase 1 so both global-load batches share one
// latency round. Row cache is f32 pitch-37 (odd -> qd groups bank-spread;
// af build = 32 ds_read2_b32 per lane instead of 128 ds_read_u16).
// LDS 18944 B; a1_s[64][136]bf16 (17408 B) aliases row_s after the barrier.
// ---------------------------------------------------------------------------
__global__ __launch_bounds__(256, 4) void k_att(
    const float* __restrict__ x, const float* __restrict__ pbe,
    const unsigned short* __restrict__ w1bf, const float* __restrict__ b1,
    const unsigned short* __restrict__ w2bf, const float* __restrict__ b2,
    float* __restrict__ att)
{
  constexpr int PH = 136;   // a1_s pitch (bf16)
  constexpr int RP = 37;    // row_s pitch (f32), odd
  __shared__ __align__(16) unsigned char smem[128 * RP * 4];    // 18944 B
  float*          row_s = (float*)smem;                         // [128][37]
  unsigned short* a1_s  = (unsigned short*)smem;                // [64][136]

  const int tid = threadIdx.x;
  const int xg0 = blockIdx.x * 64;
  const int y = blockIdx.y;
  const int b = blockIdx.z;

  const float ysf = y * SCL;
  const int y0 = (int)ysf;
  const int y1 = min(y0 + 1, HI - 1);
  const float wy = ysf - (float)y0;
  const int xi0 = (int)(xg0 * SCL);

  const int lane = tid & 63;
  const int wv = tid >> 6;        // wave id 0..3
  const int ln = lane & 15;
  const int qd = lane >> 4;
  const int m0 = wv * 16;

  const int px = m0 + ln;
  const int xg = xg0 + px;
  const float xsf = (float)xg * SCL;
  const int x0i = (int)xsf;
  const float wx = xsf - (float)x0i;
  const int xl = x0i - xi0;             // 0..32, xl+1 <= 33

  // ---- hoisted x loads: xr[kt*8+j] = x[c = kt*32+qd*8+j][y][xg]
  float xr[32];
  #pragma unroll
  for (int kt = 0; kt < 4; ++kt) {
    #pragma unroll
    for (int j = 0; j < 8; ++j) {
      const int c = kt * 32 + qd * 8 + j;
      xr[kt * 8 + j] = x[((size_t)(b * Cc + c) * Hc + y) * Wc + xg];
    }
  }

  // ---- phase 1: row_s[c][xi] = y-interp of pbe (coalesced loads, f32)
  #pragma unroll
  for (int i = 0; i < 18; ++i) {
    const int f = tid + 256 * i;        // 0..4607
    const int c = f / 36;
    const int xi = f - c * 36;
    const int xgl = min(xi0 + xi, WI - 1);
    const float* p = pbe + (size_t)(b * Cc + c) * (HI * WI);
    const float top = p[y0 * WI + xgl];
    const float bot = p[y1 * WI + xgl];
    row_s[c * RP + xi] = top + wy * (bot - top);
  }
  __syncthreads();

  // ---- build A-fragments in registers from xr + row_s
  bf16x8 af[4];
  #pragma unroll
  for (int kt = 0; kt < 4; ++kt) {
    #pragma unroll
    for (int j = 0; j < 8; ++j) {
      const int c = kt * 32 + qd * 8 + j;
      const float v0 = row_s[c * RP + xl];
      const float v1 = row_s[c * RP + xl + 1];
      af[kt][j] = (short)f2bf(xr[kt * 8 + j] + v0 + wx * (v1 - v0));
    }
  }
  __syncthreads();   // row_s dead -> region reusable as a1_s

  // ---- GEMM1: C[64m][128n] = h[64m][128k] * w1[128n][128k]^T (B from global)
  f32x4 acc[8];
  #pragma unroll
  for (int nt = 0; nt < 8; ++nt) acc[nt] = f32x4{0.f, 0.f, 0.f, 0.f};
  #pragma unroll
  for (int nt = 0; nt < 8; ++nt) {
    #pragma unroll
    for (int kt = 0; kt < 4; ++kt) {
      const bf16x8 bf = *(const bf16x8*)&w1bf[(nt * 16 + ln) * 128 + kt * 32 + qd * 8];
      acc[nt] = __builtin_amdgcn_mfma_f32_16x16x32_bf16(af[kt], bf, acc[nt], 0, 0, 0);
    }
  }

  // epilogue: relu(+bias) -> a1_s (bf16). Wave writes only its own 16 rows.
  #pragma unroll
  for (int nt = 0; nt < 8; ++nt) {
    const int n = nt * 16 + ln;
    const float bias = b1[n];
    #pragma unroll
    for (int r = 0; r < 4; ++r) {
      const int m = m0 + qd * 4 + r;
      a1_s[m * PH + n] = f2bf(fmaxf(acc[nt][r] + bias, 0.f));
    }
  }
  // no __syncthreads: each wave reads back only rows it wrote (DS in-order/wave)

  // ---- GEMM2: att[64m][16j] = a1[64m][128k] * w2e[16j][128k]^T
  f32x4 acc2 = f32x4{0.f, 0.f, 0.f, 0.f};
  #pragma unroll
  for (int kt = 0; kt < 4; ++kt) {
    const bf16x8 a2 = *(const bf16x8*)&a1_s[(m0 + ln) * PH + kt * 32 + qd * 8];
    const bf16x8 b2f = *(const bf16x8*)&w2bf[ln * 128 + kt * 32 + qd * 8];
    acc2 = __builtin_amdgcn_mfma_f32_16x16x32_bf16(a2, b2f, acc2, 0, 0, 0);
  }
  const float bias2 = b2[2 * ln];
  #pragma unroll
  for (int r = 0; r < 4; ++r) {
    const int opx = m0 + qd * 4 + r;
    const float v = fmaxf(acc2[r] + bias2, 0.f) + 0.001f;
    att[((size_t)((b * Hc + y) * Wc) + xg0 + opx) * NA + ln] = v;
  }
}

// ---------------------------------------------------------------------------
// K2: block = one image row (192 threads), thread = pixel.
// pb y-interpolated at stage time -> row_s[64][96] f32 (24 KB -> 6 blk/CU),
// delta with 4 bins in flight, register bitonic sort.
// ---------------------------------------------------------------------------
__global__ __launch_bounds__(192, 2) void k_bins(
    const float* __restrict__ pb, const float* __restrict__ att,
    float* __restrict__ out0, float* __restrict__ out1)
{
  __shared__ __align__(16) float row_s[NB][WI];   // 24576 B

  const int tid = threadIdx.x;      // = xg
  const int y = blockIdx.x;
  const int b = blockIdx.y;

  const float ysf = y * SCL;
  const int y0 = (int)ysf;
  const int y1 = min(y0 + 1, HI - 1);
  const float wy = ysf - (float)y0;

  // att for this pixel: 16 floats, contiguous — issue first (independent)
  float am[16];
  {
    const float4* ap = (const float4*)(att + ((size_t)((b * Hc + y) * Wc) + tid) * NA);
    const float4 a0 = ap[0], a1 = ap[1], a2 = ap[2], a3 = ap[3];
    am[0] = a0.x;  am[1] = a0.y;  am[2] = a0.z;  am[3] = a0.w;
    am[4] = a1.x;  am[5] = a1.y;  am[6] = a1.z;  am[7] = a1.w;
    am[8] = a2.x;  am[9] = a2.y;  am[10] = a2.z; am[11] = a2.w;
    am[12] = a3.x; am[13] = a3.y; am[14] = a3.z; am[15] = a3.w;
  }

  // ---- stage y-interpolated pb rows for all 64 bins: 1536 float4 positions
  #pragma unroll
  for (int i = 0; i < 8; ++i) {
    const int u = tid + 192 * i;          // 0..1535
    const int k = u / 24;
    const int g = u - k * 24;             // float4 group in row
    const float* base = pb + (size_t)(b * NB + k) * (HI * WI);
    const float4 t4 = *(const float4*)&base[y0 * WI + g * 4];
    const float4 b4 = *(const float4*)&base[y1 * WI + g * 4];
    float4 r;
    r.x = t4.x + wy * (b4.x - t4.x);
    r.y = t4.y + wy * (b4.y - t4.y);
    r.z = t4.z + wy * (b4.z - t4.z);
    r.w = t4.w + wy * (b4.w - t4.w);
    *(float4*)&row_s[k][g * 4] = r;
  }
  __syncthreads();

  const float xsf = tid * SCL;
  const int x0 = (int)xsf;          // <= 94
  const float wx = xsf - (float)x0;

  const size_t obase = (size_t)(b * NB) * (Hc * Wc) + (size_t)y * Wc + tid;
  float v[NB];

  // ---- delta: 4 bins in flight -> 4 independent rcp chains
  #pragma unroll
  for (int kb = 0; kb < NB; kb += 4) {
    float bc[4], dl[4];
    #pragma unroll
    for (int q = 0; q < 4; ++q) {
      const int k = kb + q;
      const float v0 = row_s[k][x0], v1 = row_s[k][x0 + 1];
      bc[q] = v0 + wx * (v1 - v0);
      dl[q] = 0.f;
    }
    #pragma unroll
    for (int j = 0; j < NA; ++j) {
      const float a = am[j];
      #pragma unroll
      for (int q = 0; q < 4; ++q) {
        const float d = a - bc[q];
        const float rq = fmaf(300.f * d, d, 1.f);
        dl[q] = fmaf(d, rcp_fast(rq), dl[q]);
      }
    }
    #pragma unroll
    for (int q = 0; q < 4; ++q) {
      const float bnc = fmaf(dl[q], 1.f / 16.f, bc[q]);
      out0[obase + (size_t)(kb + q) * (Hc * Wc)] = bnc;
      v[kb + q] = fmaf(9.999f, bnc, 0.001f);
    }
  }

  // ---- fully-unrolled bitonic sort on 64 registers (ascending)
  #pragma unroll
  for (int size = 2; size <= NB; size <<= 1) {
    #pragma unroll
    for (int stride = size >> 1; stride >= 1; stride >>= 1) {
      #pragma unroll
      for (int i = 0; i < NB; ++i) {
        if ((i & stride) == 0) {
          const int j = i | stride;
          const bool asc = ((i & size) == 0);
          const float a = v[i], c = v[j];
          const float lo = fminf(a, c), hi = fmaxf(a, c);
          v[i] = asc ? lo : hi;
          v[j] = asc ? hi : lo;
        }
      }
    }
  }

  #pragma unroll
  for (int k = 0; k < NB; ++k) {
    out1[obase + (size_t)k * (Hc * Wc)] = fminf(fmaxf(v[k], 0.001f), 10.0f);
  }
}

// ---------------------------------------------------------------------------
extern "C" void kernel_launch(void* const* d_in, const int* in_sizes, int n_in,
                              void* d_out, int out_size, void* d_ws, size_t ws_size,
                              hipStream_t stream) {
  const float* x   = (const float*)d_in[0];   // (4,128,192,192)
  const float* pb  = (const float*)d_in[1];   // (4,64,96,96)
  const float* pbe = (const float*)d_in[2];   // (4,128,96,96)
  const float* w1  = (const float*)d_in[3];   // (128,128)
  const float* b1  = (const float*)d_in[4];   // (128,)
  const float* w2  = (const float*)d_in[5];   // (32,128)
  const float* b2  = (const float*)d_in[6];   // (32,)

  float* out0 = (float*)d_out;                       // bin_new_centers
  float* out1 = out0 + (size_t)Bc * NB * Hc * Wc;    // bin_centers

  // ws layout: [w1bf 32KB][w2bf 4KB][pad to 64KB][att f32 9.4MB]
  unsigned short* w1bf = (unsigned short*)d_ws;
  unsigned short* w2bf = w1bf + 16384;
  float* att = (float*)((char*)d_ws + 65536);        // [b][y][x][j]

  k_prep<<<72, 256, 0, stream>>>(w1, w2, w1bf, w2bf);

  dim3 g1(Wc / 64, Hc, Bc);
  k_att<<<g1, 256, 0, stream>>>(x, pbe, w1bf, b1, w2bf, b2, att);

  dim3 g2(Hc, Bc);
  k_bins<<<g2, 192, 0, stream>>>(pb, att, out0, out1);
}